// Round 14
// baseline (447.533 us; speedup 1.0000x reference)
//
#include <hip/hip_runtime.h>
#include <hip/hip_bf16.h>

#define D_MODEL 128
#define SEQ_L   4096
#define BATCH   128
#define NSEG    8                     // mean segments (512 tokens each)
#define TOKS2   512                   // tokens per K2 block

typedef float f4 __attribute__((ext_vector_type(4)));
typedef float f32x4 __attribute__((ext_vector_type(4)));
typedef short bf16x8 __attribute__((ext_vector_type(8)));

__device__ __forceinline__ unsigned short f2bf(float f) {
    union { float f; unsigned u; } v; v.f = f;
    unsigned r = v.u + 0x7FFFu + ((v.u >> 16) & 1u);
    return (unsigned short)(r >> 16);
}

// ---------------- K1: partial mean over L ----------------
// grid (NSEG, 128) = 1024 blocks, 256 threads = 4 blocks/CU, 8-deep independent loads.
__global__ __launch_bounds__(256) void kmean(const float* __restrict__ x,
                                             float* __restrict__ part) {
    int seg = blockIdx.x, b = blockIdx.y, t = threadIdx.x;
    int c4 = t & 31, ph = t >> 5;                 // ph 0..7
    const f4* xb = reinterpret_cast<const f4*>(x + (size_t)b * SEQ_L * D_MODEL);
    int l0 = seg * (SEQ_L / NSEG);                // 512 tokens per block

    f4 acc = {0.f, 0.f, 0.f, 0.f};
    #pragma unroll
    for (int o = 0; o < (SEQ_L / NSEG) / 64; ++o) {   // 8 sweeps of 64 tokens
        f4 R[8];
        #pragma unroll
        for (int j = 0; j < 8; ++j)
            R[j] = xb[(size_t)(l0 + o * 64 + ph + j * 8) * 32 + c4];
        R[0] += R[4]; R[1] += R[5]; R[2] += R[6]; R[3] += R[7];
        R[0] += R[2]; R[1] += R[3];
        acc += R[0] + R[1];
    }
    __shared__ f4 red[256];
    red[t] = acc;
    __syncthreads();
    if (t < 32) {
        f4 s = red[t];
        #pragma unroll
        for (int p = 1; p < 8; ++p) s += red[t + 32 * p];
        reinterpret_cast<f4*>(part + ((size_t)b * NSEG + seg) * D_MODEL)[t] = s;
    }
}

// ---------------- K2: redundant MLP + fused conv/MFMA ----------------
template<bool GUARD>
__device__ __forceinline__ void load6(const float* __restrict__ xb, int gr0, int c4, f4 R[6]) {
    #pragma unroll
    for (int j = 0; j < 6; ++j) {
        int gr = gr0 + j;
        if (GUARD) {
            bool ok = (gr >= 0) && (gr < SEQ_L);
            int grc = ok ? gr : 0;
            f4 v = reinterpret_cast<const f4*>(xb + (size_t)grc * D_MODEL)[c4];
            f4 z = {0.f, 0.f, 0.f, 0.f};
            R[j] = ok ? v : z;
        } else {
            R[j] = reinterpret_cast<const f4*>(xb + (size_t)gr * D_MODEL)[c4];
        }
    }
}

// grid (SEQ_L/TOKS2=8, 128) = 1024 blocks, 512 threads = 2 blocks/CU (proven 84-VGPR point).
__global__ __launch_bounds__(512, 2) void kconv(const float* __restrict__ x,
                                                const float* __restrict__ part,
                                                const float* __restrict__ W1,
                                                const float* __restrict__ b1,
                                                const float* __restrict__ W2,
                                                const float* __restrict__ b2,
                                                const float* __restrict__ Wc,
                                                const float* __restrict__ bc,
                                                float* __restrict__ out) {
    __shared__ __align__(16) unsigned short y_lds[2][64][132];   // 33.8 KB
    __shared__ __align__(16) float wv_lds[3][128];

    const int t = threadIdx.x, b = blockIdx.y;
    const int sb = blockIdx.x * TOKS2;
    const float* xb = x + (size_t)b * SEQ_L * D_MODEL;
    float* outb = out + (size_t)b * SEQ_L * D_MODEL;

    int c4 = t & 31, rg = t >> 5;            // rg 0..15: rows rg*4..rg*4+3 of each half
    int lane = t & 63, wid = t >> 6;
    int r = lane & 15, q = lane >> 4, kb = q * 8;
    int co0 = wid * 16;

    // issue tile-0 x loads FIRST — latency hides under the MLP below
    f4 R[2][6];
    if (sb == 0) load6<true>(xb, sb + rg * 4 - 1, c4, R[0]);
    else         load6<false>(xb, sb + rg * 4 - 1, c4, R[0]);

    // ---- redundant per-block MLP: part (L2-hot) -> wv_lds[3][128] ----
    {
        int c = t >> 2, p = t & 3;
        f4 mv[8];
        #pragma unroll
        for (int d4 = 0; d4 < 8; ++d4) mv[d4] = (f4){0.f, 0.f, 0.f, 0.f};
        #pragma unroll
        for (int s = 0; s < NSEG; ++s) {
            const f4* ps = reinterpret_cast<const f4*>(part + ((size_t)c * NSEG + s) * D_MODEL + p * 32);
            #pragma unroll
            for (int d4 = 0; d4 < 8; ++d4) mv[d4] += ps[d4];
        }
        #pragma unroll
        for (int d4 = 0; d4 < 8; ++d4) mv[d4] *= (1.0f / (float)SEQ_L);

        float h[32];
        #pragma unroll
        for (int j = 0; j < 32; ++j) {
            const f4* w1r = reinterpret_cast<const f4*>(W1 + j * 128 + p * 32);
            f4 s4 = {0.f, 0.f, 0.f, 0.f};
            #pragma unroll
            for (int d4 = 0; d4 < 8; ++d4) s4 += mv[d4] * w1r[d4];
            float s = s4[0] + s4[1] + s4[2] + s4[3];
            s += __shfl_xor(s, 1);
            s += __shfl_xor(s, 2);               // full 128-dot across 4 partners
            s += b1[j];
            h[j] = 0.5f * s * (1.0f + erff(s * 0.70710678118654752f)); // exact gelu
        }
        if (p == 0) {
            float lg[3], mx = -1e30f;
            #pragma unroll
            for (int k = 0; k < 3; ++k) {
                float s = b2[k];
                #pragma unroll
                for (int j = 0; j < 32; ++j) s += h[j] * W2[k * 32 + j];
                lg[k] = s; mx = fmaxf(mx, s);
            }
            float e[3], den = 0.f;
            #pragma unroll
            for (int k = 0; k < 3; ++k) { e[k] = __expf(lg[k] - mx); den += e[k]; }
            float inv = 1.0f / den;
            #pragma unroll
            for (int k = 0; k < 3; ++k) wv_lds[k][c] = e[k] * inv;
        }
    }
    __syncthreads();   // wv_lds ready

    // conv taps + Wc A-fragments (reg cvt from fp32, L2/L3-hot) + bias
    f4 w0 = *reinterpret_cast<const f4*>(&wv_lds[0][c4 * 4]);
    f4 w1 = *reinterpret_cast<const f4*>(&wv_lds[1][c4 * 4]);
    f4 w2 = *reinterpret_cast<const f4*>(&wv_lds[2][c4 * 4]);

    bf16x8 awc[4];
    #pragma unroll
    for (int kc = 0; kc < 4; ++kc) {
        const float* wr = Wc + (size_t)(co0 + r) * D_MODEL + kc * 32 + kb;
        f4 a = *reinterpret_cast<const f4*>(wr);
        f4 bb = *reinterpret_cast<const f4*>(wr + 4);
        bf16x8 fr;
        fr[0] = (short)f2bf(a[0]);  fr[1] = (short)f2bf(a[1]);
        fr[2] = (short)f2bf(a[2]);  fr[3] = (short)f2bf(a[3]);
        fr[4] = (short)f2bf(bb[0]); fr[5] = (short)f2bf(bb[1]);
        fr[6] = (short)f2bf(bb[2]); fr[7] = (short)f2bf(bb[3]);
        awc[kc] = fr;
    }
    f4 bcv = *reinterpret_cast<const f4*>(bc + co0 + q * 4);

    // ---- pipelined conv/MFMA loop: 8 half-tiles of 64 tokens, dual-R, 1 barrier/half ----
    #pragma unroll
    for (int ht = 0; ht < TOKS2 / 64; ++ht) {
        const int cur = ht & 1, nxt = cur ^ 1;
        int base = sb + ht * 64;
        // issue NEXT half's loads first — fly under conv+barrier+MFMA+stores
        if (ht < TOKS2 / 64 - 1) {
            int nb = base + 64;
            if (nb + 64 == SEQ_L) load6<true>(xb, nb + rg * 4 - 1, c4, R[nxt]);
            else                  load6<false>(xb, nb + rg * 4 - 1, c4, R[nxt]);
        }
        // conv (consumes R[cur]) + LDS write
        #pragma unroll
        for (int j = 0; j < 4; ++j) {
            f4 y = R[cur][j] * w0 + R[cur][j + 1] * w1 + R[cur][j + 2] * w2;
            ushort4 yb;
            yb.x = f2bf(y[0]); yb.y = f2bf(y[1]); yb.z = f2bf(y[2]); yb.w = f2bf(y[3]);
            *reinterpret_cast<ushort4*>(&y_lds[cur][rg * 4 + j][c4 * 4]) = yb;
        }
        __syncthreads();   // y_lds[cur] visible

        // MFMA: wave = 64 tokens x 16 co
        f32x4 acc[4];
        #pragma unroll
        for (int g = 0; g < 4; ++g) acc[g] = (f32x4){0.f, 0.f, 0.f, 0.f};
        #pragma unroll
        for (int g = 0; g < 4; ++g)
            #pragma unroll
            for (int kc = 0; kc < 4; ++kc) {
                bf16x8 bv = *reinterpret_cast<const bf16x8*>(&y_lds[cur][g * 16 + r][kc * 32 + kb]);
                acc[g] = __builtin_amdgcn_mfma_f32_16x16x32_bf16(awc[kc], bv, acc[g], 0, 0, 0);
            }

        // epilogue: token = base+g*16+r, co = co0+q*4+reg
        #pragma unroll
        for (int g = 0; g < 4; ++g) {
            int tok = base + g * 16 + r;
            *reinterpret_cast<f4*>(outb + (size_t)tok * D_MODEL + co0 + q * 4) = acc[g] + bcv;
        }
        // no trailing barrier: buffer cur is next rewritten at ht+2, after barrier ht+1
        // which transitively proves all waves completed this MFMA read.
    }
}

extern "C" void kernel_launch(void* const* d_in, const int* in_sizes, int n_in,
                              void* d_out, int out_size, void* d_ws, size_t ws_size,
                              hipStream_t stream) {
    const float* x  = (const float*)d_in[0];
    const float* W1 = (const float*)d_in[1];
    const float* b1 = (const float*)d_in[2];
    const float* W2 = (const float*)d_in[3];
    const float* b2 = (const float*)d_in[4];
    const float* Wc = (const float*)d_in[5];
    const float* bc = (const float*)d_in[6];
    float* out = (float*)d_out;

    float* part = (float*)d_ws;   // 128*8*128*4 = 512 KB

    kmean<<<dim3(NSEG, BATCH), 256, 0, stream>>>(x, part);
    kconv<<<dim3(SEQ_L / TOKS2, BATCH), 512, 0, stream>>>(x, part, W1, b1, W2, b2, Wc, bc, out);
}

// Round 15
// 248.956 us; speedup vs baseline: 1.7976x; 1.7976x over previous
//
#include <hip/hip_runtime.h>
#include <hip/hip_bf16.h>

#define D_MODEL 128
#define SEQ_L   4096
#define BATCH   128
#define NSEG    16    // kmean segments (256 tokens each)

typedef float f4 __attribute__((ext_vector_type(4)));
typedef float f32x4 __attribute__((ext_vector_type(4)));
typedef short bf16x8 __attribute__((ext_vector_type(8)));

__device__ __forceinline__ unsigned short f2bf(float f) {
    union { float f; unsigned u; } v; v.f = f;
    unsigned r = v.u + 0x7FFFu + ((v.u >> 16) & 1u);
    return (unsigned short)(r >> 16);
}

// ---------------- kernel 1: partial mean over L (+ folded Wc->bf16 cvt) ----------------
// grid (NSEG+1, 128), 512 threads. 16 INDEPENDENT loads -> tree sum.
// 2176 blocks, 4 blocks/CU -> 32 waves/CU, 16 loads deep: ~32 KB/CU in flight (BW-bound).
__global__ __launch_bounds__(512) void kmean(const float* __restrict__ x,
                                             float* __restrict__ part,
                                             const float* __restrict__ Wc,
                                             unsigned short* __restrict__ wcb) {
    if (blockIdx.x == NSEG) {
        if (blockIdx.y < 8) {
            int i = blockIdx.y * 512 + threadIdx.x;   // 4096 threads x 4 floats = 16384
            f4 v = reinterpret_cast<const f4*>(Wc)[i];
            ushort4 o;
            o.x = f2bf(v[0]); o.y = f2bf(v[1]); o.z = f2bf(v[2]); o.w = f2bf(v[3]);
            reinterpret_cast<ushort4*>(wcb)[i] = o;
        }
        return;
    }
    int seg = blockIdx.x, b = blockIdx.y;
    int t = threadIdx.x;
    int c4 = t & 31, ph = t >> 5;                 // ph: 0..15
    const f4* xb = reinterpret_cast<const f4*>(x + (size_t)b * SEQ_L * D_MODEL);
    int l0 = seg * (SEQ_L / NSEG);                // 256 tokens per block

    // 16 independent 16B loads, all in flight before any use
    f4 R[16];
    #pragma unroll
    for (int j = 0; j < 16; ++j)
        R[j] = xb[(size_t)(l0 + ph + j * 16) * 32 + c4];

    // tree sum
    #pragma unroll
    for (int s = 8; s >= 1; s >>= 1)
        #pragma unroll
        for (int j = 0; j < s; ++j) R[j] += R[j + s];

    __shared__ f4 red[512];
    red[t] = R[0];
    __syncthreads();
    if (t < 32) {
        f4 s = red[t];
        #pragma unroll
        for (int p = 1; p < 16; ++p) s += red[t + 32 * p];
        reinterpret_cast<f4*>(part + ((size_t)b * NSEG + seg) * D_MODEL)[t] = s;
    }
}

// ---------------- kernel 2: per-channel MLP + softmax -> w[3][128] ----------------
__global__ __launch_bounds__(128) void kweights(const float* __restrict__ part,
                                                const float* __restrict__ W1,
                                                const float* __restrict__ b1,
                                                const float* __restrict__ W2,
                                                const float* __restrict__ b2,
                                                float* __restrict__ w) {
    int c = threadIdx.x; // 0..127
    f4 mv[32];
    #pragma unroll
    for (int d4 = 0; d4 < 32; ++d4) mv[d4] = (f4){0.f, 0.f, 0.f, 0.f};
    for (int s = 0; s < NSEG; ++s) {
        const f4* ps = reinterpret_cast<const f4*>(part + ((size_t)c * NSEG + s) * D_MODEL);
        #pragma unroll
        for (int d4 = 0; d4 < 32; ++d4) mv[d4] += ps[d4];
    }
    #pragma unroll
    for (int d4 = 0; d4 < 32; ++d4) mv[d4] *= (1.0f / (float)SEQ_L);

    float h[32];
    #pragma unroll
    for (int j = 0; j < 32; ++j) {
        const f4* w1r = reinterpret_cast<const f4*>(W1 + j * 128);
        f4 s4 = {0.f, 0.f, 0.f, 0.f};
        #pragma unroll
        for (int d4 = 0; d4 < 32; ++d4) s4 += mv[d4] * w1r[d4];
        float s = s4[0] + s4[1] + s4[2] + s4[3] + b1[j];
        h[j] = 0.5f * s * (1.0f + erff(s * 0.70710678118654752f)); // exact gelu
    }
    float lg[3];
    float mx = -1e30f;
    #pragma unroll
    for (int k = 0; k < 3; ++k) {
        float s = b2[k];
        #pragma unroll
        for (int j = 0; j < 32; ++j) s += h[j] * W2[k * 32 + j];
        lg[k] = s;
        mx = fmaxf(mx, s);
    }
    float e[3], den = 0.f;
    #pragma unroll
    for (int k = 0; k < 3; ++k) { e[k] = __expf(lg[k] - mx); den += e[k]; }
    float inv = 1.0f / den;
    #pragma unroll
    for (int k = 0; k < 3; ++k) w[k * 128 + c] = e[k] * inv;
}

// ---------------- kernel 3: fused conv + matmul (r6 verified, minus trailing barrier) ----------------
template<bool GUARD>
__device__ __forceinline__ void load6(const float* __restrict__ xb, int gr0, int c4, f4 R[6]) {
    #pragma unroll
    for (int j = 0; j < 6; ++j) {
        int gr = gr0 + j;
        if (GUARD) {
            bool ok = (gr >= 0) && (gr < SEQ_L);
            int grc = ok ? gr : 0;
            f4 v = reinterpret_cast<const f4*>(xb + (size_t)grc * D_MODEL)[c4];
            f4 z = {0.f, 0.f, 0.f, 0.f};
            R[j] = ok ? v : z;
        } else {
            R[j] = reinterpret_cast<const f4*>(xb + (size_t)gr * D_MODEL)[c4];
        }
    }
}

// grid (SEQ_L/256, BATCH), 512 threads = 8 waves; wave w -> co block w*16.
// One barrier per 64-token half-tile. Trailing barrier removed: buffer buf=i&1 is
// next rewritten at conv(i+2), which is after barrier(i+1); reaching barrier(i+1)
// requires (program order) having finished MFMA(i) -> no race on y_lds[buf].
__global__ __launch_bounds__(512, 2) void kconv(const float* __restrict__ x,
                                                const float* __restrict__ wv,
                                                const unsigned short* __restrict__ wcb,
                                                const float* __restrict__ bc,
                                                float* __restrict__ out) {
    __shared__ __align__(16) unsigned short y_lds[2][64][132];

    int t = threadIdx.x;
    int b = blockIdx.y;
    int base = blockIdx.x * 256;
    const float* xb = x + (size_t)b * SEQ_L * D_MODEL;
    float* outb = out + (size_t)b * SEQ_L * D_MODEL;

    int c4 = t & 31, rg = t >> 5;            // rg: 0..15, owns rows rg*4..rg*4+3 of half
    int lane = t & 63, wid = t >> 6;
    int r = lane & 15, q = lane >> 4, kb = q * 8;
    int co0 = wid * 16;

    // conv taps for this thread's channel quad
    f4 w0 = reinterpret_cast<const f4*>(wv)[c4];
    f4 w1 = reinterpret_cast<const f4*>(wv + 128)[c4];
    f4 w2 = reinterpret_cast<const f4*>(wv + 256)[c4];

    // Wc A-fragments, loaded once (L2-hot)
    bf16x8 awc[4];
    #pragma unroll
    for (int kc = 0; kc < 4; ++kc)
        awc[kc] = *reinterpret_cast<const bf16x8*>(wcb + (size_t)(co0 + r) * D_MODEL + kc * 32 + kb);

    f4 bcv = *reinterpret_cast<const f4*>(bc + co0 + q * 4);

    // prologue: load half 0
    f4 R[6];
    if (base == 0) load6<true>(xb, base + rg * 4 - 1, c4, R);
    else           load6<false>(xb, base + rg * 4 - 1, c4, R);

    #pragma unroll
    for (int i = 0; i < 4; ++i) {
        int buf = i & 1;
        // y-compute (waits this half's loads) + LDS write
        #pragma unroll
        for (int j = 0; j < 4; ++j) {
            f4 y = R[j] * w0 + R[j + 1] * w1 + R[j + 2] * w2;
            ushort4 yb;
            yb.x = f2bf(y[0]); yb.y = f2bf(y[1]); yb.z = f2bf(y[2]); yb.w = f2bf(y[3]);
            *reinterpret_cast<ushort4*>(&y_lds[buf][rg * 4 + j][c4 * 4]) = yb;
        }
        // issue NEXT half's loads (in flight across the barrier)
        if (i < 3) {
            int ntok0 = base + (i + 1) * 64;
            if (ntok0 + 64 == SEQ_L) load6<true>(xb, ntok0 + rg * 4 - 1, c4, R);
            else                     load6<false>(xb, ntok0 + rg * 4 - 1, c4, R);
        }
        __syncthreads();   // y_lds[buf] visible

        // MFMA: wave = 64 tokens x 16 co
        f32x4 acc[4];
        #pragma unroll
        for (int g = 0; g < 4; ++g) acc[g] = (f32x4){0.f, 0.f, 0.f, 0.f};
        #pragma unroll
        for (int g = 0; g < 4; ++g)
            #pragma unroll
            for (int kc = 0; kc < 4; ++kc) {
                bf16x8 bv = *reinterpret_cast<const bf16x8*>(&y_lds[buf][g * 16 + r][kc * 32 + kb]);
                acc[g] = __builtin_amdgcn_mfma_f32_16x16x32_bf16(awc[kc], bv, acc[g], 0, 0, 0);
            }

        // epilogue
        int tokt = base + i * 64;
        #pragma unroll
        for (int g = 0; g < 4; ++g) {
            int tok = tokt + g * 16 + r;
            *reinterpret_cast<f4*>(outb + (size_t)tok * D_MODEL + co0 + q * 4) = acc[g] + bcv;
        }
        // trailing barrier removed (safe per double-buffer transitivity; r8-validated)
    }
}

extern "C" void kernel_launch(void* const* d_in, const int* in_sizes, int n_in,
                              void* d_out, int out_size, void* d_ws, size_t ws_size,
                              hipStream_t stream) {
    const float* x  = (const float*)d_in[0];
    const float* W1 = (const float*)d_in[1];
    const float* b1 = (const float*)d_in[2];
    const float* W2 = (const float*)d_in[3];
    const float* b2 = (const float*)d_in[4];
    const float* Wc = (const float*)d_in[5];
    const float* bc = (const float*)d_in[6];
    float* out = (float*)d_out;

    char* ws = (char*)d_ws;
    float* part = (float*)ws;                                 // 128*16*128*4 = 1 MB
    float* w    = (float*)(ws + 1048576);                     // 1.5 KB
    unsigned short* wcb = (unsigned short*)(ws + 1052672);    // 32 KB

    kmean<<<dim3(NSEG + 1, BATCH), 512, 0, stream>>>(x, part, Wc, wcb);
    kweights<<<1, 128, 0, stream>>>(part, W1, b1, W2, b2, w);
    kconv<<<dim3(SEQ_L / 256, BATCH), 512, 0, stream>>>(x, w, wcb, bc, out);
}